// Round 10
// baseline (213.072 us; speedup 1.0000x reference)
//
#include <hip/hip_runtime.h>

// CrossAttention on MI355X (gfx950), bf16 MFMA path.
// B=4, Lq=2048, Lkv=512, dim_q=1024, dim_kv=768, H=8, hd=128.
// R10: retile the two M=8192 GEMMs (Q-proj, O-proj) from 128x128/512 blocks
//      (2 blocks/CU, 25% occupancy cap) to 128x64/1024 blocks (4 blocks/CU,
//      16 waves/CU — m97's plateau regime). KV-GEMM + attn unchanged (R7/R9
//      stable baseline).

typedef unsigned short u16;
typedef unsigned int u32;
using short8  = __attribute__((ext_vector_type(8))) short;   // 8 x bf16 (4 VGPRs)
using floatx4 = __attribute__((ext_vector_type(4))) float;

__device__ inline u16 f2bf(float x) {
  union { float f; u32 u; } v; v.f = x;
  u32 r = (v.u + 0x7fffu + ((v.u >> 16) & 1u)) >> 16;  // RNE
  return (u16)r;
}

__device__ inline float fast_exp2(float x) {
#if __has_builtin(__builtin_amdgcn_exp2f)
  return __builtin_amdgcn_exp2f(x);   // v_exp_f32 (natively exp2)
#else
  return exp2f(x);
#endif
}

#define MFMA(a, b, c) __builtin_amdgcn_mfma_f32_16x16x32_bf16(a, b, c, 0, 0, 0)

__device__ inline void async_lds16(const void* g, void* l) {
  __builtin_amdgcn_global_load_lds(
      (const __attribute__((address_space(1))) void*)g,
      (__attribute__((address_space(3))) void*)l, 16, 0, 0);
}

// ------------- fp32 -> bf16 cast, q and kv in one launch -------------
__global__ void cvt_all(const float* __restrict__ q, const float* __restrict__ kv,
                        u16* __restrict__ q_bf, u16* __restrict__ kv_bf) {
  int i = blockIdx.x * 256 + threadIdx.x;
  const float* src; u16* dst; int idx;
  if (i < 1048576) { src = q;  dst = q_bf;  idx = i; }
  else             { src = kv; dst = kv_bf; idx = i - 1048576; }
  float4 a = ((const float4*)src)[2 * idx];
  float4 b = ((const float4*)src)[2 * idx + 1];
  u16 t[8] = {f2bf(a.x), f2bf(a.y), f2bf(a.z), f2bf(a.w),
              f2bf(b.x), f2bf(b.y), f2bf(b.z), f2bf(b.w)};
  ((short8*)dst)[idx] = *(short8*)t;
}

// ------------- all four W [K][N] fp32 -> Wt [N][K] bf16, one launch -------------
__global__ __launch_bounds__(256)
void transpose_all(const float* __restrict__ Wq, const float* __restrict__ Wk,
                   const float* __restrict__ Wv, const float* __restrict__ Wo,
                   u16* __restrict__ WqT, u16* __restrict__ WkvT, u16* __restrict__ WoT) {
  __shared__ float tile[64][68];
  const int z = blockIdx.z;
  const float* W; u16* Wt; int K;
  if      (z == 0) { W = Wq; Wt = WqT;               K = 1024; }
  else if (z == 1) { W = Wk; Wt = WkvT;              K = 768;  }
  else if (z == 2) { W = Wv; Wt = WkvT + 1024 * 768; K = 768;  }
  else             { W = Wo; Wt = WoT;               K = 1024; }
  const int k0 = blockIdx.y * 64, n0 = blockIdx.x * 64;
  if (k0 >= K) return;
  const int N = 1024;
  const int t = threadIdx.x;
  for (int p = 0; p < 4; ++p) {
    int cid = p * 256 + t;
    int row = cid >> 4, c = cid & 15;
    float4 v = *(const float4*)&W[(long)(k0 + row) * N + n0 + c * 4];
    tile[row][c * 4 + 0] = v.x; tile[row][c * 4 + 1] = v.y;
    tile[row][c * 4 + 2] = v.z; tile[row][c * 4 + 3] = v.w;
  }
  __syncthreads();
  for (int p = 0; p < 2; ++p) {
    int oc = p * 256 + t;
    int n = oc >> 3, c = oc & 7;
    u16 tmp[8];
    for (int s = 0; s < 8; ++s) tmp[s] = f2bf(tile[c * 8 + s][n]);
    *(short8*)&Wt[(long)(n0 + n) * K + k0 + c * 8] = *(short8*)tmp;
  }
}

// ---------------- bf16 GEMM 128x128 (KV-projection only, unchanged) ----------------
__global__ __launch_bounds__(256)
void gemm_bt(const u16* __restrict__ A, const u16* __restrict__ Bt,
             u16* __restrict__ Cb, float* __restrict__ Cf,
             const float* __restrict__ bias, u16* __restrict__ vt_out,
             int M, int N, int K, int ldc, int mt_per_xcd) {
  __shared__ u16 smem[17664];               // staging 32KB; epilogue [128][138]
  u16* As = smem;                           // [128][64]
  u16* Bs = smem + 8192;                    // [128][64]
  const int tid  = threadIdx.x;
  const int wave = tid >> 6, lane = tid & 63;
  const int l15  = lane & 15, quad = lane >> 4;
  const int wm   = (wave >> 1) * 64, wn = (wave & 1) * 64;
  const int lin  = blockIdx.x;
  const int xcd  = lin & 7, slot = lin >> 3;
  const int mt   = xcd * mt_per_xcd + (slot % mt_per_xcd);
  const int nti  = slot / mt_per_xcd;
  const long m0  = (long)mt * 128, n0 = (long)nti * 128;
  const int lrow = lane >> 3;
  const int lk   = (lane & 7) * 8;

  floatx4 acc[4][4] = {};

  for (int k0 = 0; k0 < K; k0 += 64) {
    for (int c = 0; c < 4; ++c) {
      int rbase = (wave * 4 + c) * 8;
      async_lds16(A  + (m0 + rbase + lrow) * (long)K + k0 + lk, &As[(wave * 4 + c) * 512]);
      async_lds16(Bt + (n0 + rbase + lrow) * (long)K + k0 + lk, &Bs[(wave * 4 + c) * 512]);
    }
    __syncthreads();
    for (int kc = 0; kc < 2; ++kc) {
      short8 af[4], bfr[4];
      for (int i = 0; i < 4; ++i)
        af[i] = *(const short8*)&As[(wm + i * 16 + l15) * 64 + kc * 32 + quad * 8];
      for (int j = 0; j < 4; ++j)
        bfr[j] = *(const short8*)&Bs[(wn + j * 16 + l15) * 64 + kc * 32 + quad * 8];
      for (int i = 0; i < 4; ++i)
        for (int j = 0; j < 4; ++j)
          acc[i][j] = MFMA(af[i], bfr[j], acc[i][j]);
    }
    __syncthreads();
  }

  if (Cf) {
    for (int i = 0; i < 4; ++i)
      for (int j = 0; j < 4; ++j) {
        long row = m0 + wm + i * 16 + quad * 4;
        long col = n0 + wn + j * 16 + l15;
        float b = bias ? bias[col] : 0.f;
        for (int r = 0; r < 4; ++r) Cf[(row + r) * (long)ldc + col] = acc[i][j][r] + b;
      }
    return;
  }
  for (int i = 0; i < 4; ++i)
    for (int j = 0; j < 4; ++j)
      for (int r = 0; r < 4; ++r)
        smem[(wm + i * 16 + quad * 4 + r) * 138 + wn + j * 16 + l15] = f2bf(acc[i][j][r]);
  __syncthreads();
  if (vt_out && nti >= 8) {
    const int h  = nti - 8;
    const int bq = (int)(m0 >> 9);
    const int l0 = (int)(m0 & 511);
    u16* vbase = vt_out + ((long)(bq * 8 + h) * 128) * 512;
    for (int p = 0; p < 8; ++p) {
      int cid = p * 256 + tid;
      int d = cid >> 4, c = cid & 15;
      u16 tmp[8];
      for (int s = 0; s < 8; ++s) tmp[s] = smem[(c * 8 + s) * 138 + d];
      *(short8*)&vbase[(long)d * 512 + l0 + c * 8] = *(short8*)tmp;
    }
  } else {
    for (int p = 0; p < 8; ++p) {
      int cid = p * 256 + tid;
      int row = cid >> 4, c = cid & 15;
      short8 v = *(const short8*)&smem[row * 138 + c * 8];
      *(short8*)&Cb[(m0 + row) * (long)ldc + n0 + c * 8] = v;
    }
  }
}

// ---------------- bf16 GEMM 128x64 (Q-proj / O-proj), 1024 blocks ----------------
// M=8192, N=1024, 64 m-tiles x 16 n-tiles. 4 waves: wm=(wave&1)*64,
// wn=(wave>>1)*32; each wave 64x32 = 4x2 acc frags. LDS 24 KB -> 4 blocks/CU
// (grid-capped), 16 waves/CU vs old 8.
__global__ __launch_bounds__(256)
void gemm_n64(const u16* __restrict__ A, const u16* __restrict__ Bt,
              u16* __restrict__ Cb, float* __restrict__ Cf,
              const float* __restrict__ bias, int K, int ldc) {
  __shared__ u16 smem[12288];   // As [128][64] + Bs [64][64]; epilogue [128][72]
  u16* As = smem;
  u16* Bs = smem + 8192;
  const int tid  = threadIdx.x;
  const int wave = tid >> 6, lane = tid & 63;
  const int l15  = lane & 15, quad = lane >> 4;
  const int wm   = (wave & 1) * 64;
  const int wn   = (wave >> 1) * 32;
  const int lin  = blockIdx.x;
  const int xcd  = lin & 7, slot = lin >> 3;     // slot 0..127
  const int mt   = xcd * 8 + (slot & 7);         // 0..63
  const int nti  = slot >> 3;                    // 0..15
  const long m0  = (long)mt * 128, n0 = (long)nti * 64;
  const int lrow = lane >> 3;                    // 0..7
  const int lk   = (lane & 7) * 8;               // 0..56

  floatx4 acc[4][2] = {};

  for (int k0 = 0; k0 < K; k0 += 64) {
    // A tile [128][64]: 16 insts x 1KB (8 rows each); wave does 4
    for (int c = 0; c < 4; ++c) {
      int inst = wave * 4 + c;
      async_lds16(A + (m0 + inst * 8 + lrow) * (long)K + k0 + lk, &As[inst * 512]);
    }
    // B tile [64][64]: 8 insts; wave does 2
    for (int c = 0; c < 2; ++c) {
      int inst = wave * 2 + c;
      async_lds16(Bt + (n0 + inst * 8 + lrow) * (long)K + k0 + lk, &Bs[inst * 512]);
    }
    __syncthreads();
    for (int kc = 0; kc < 2; ++kc) {
      short8 af[4], bfr[2];
      for (int i = 0; i < 4; ++i)
        af[i] = *(const short8*)&As[(wm + i * 16 + l15) * 64 + kc * 32 + quad * 8];
      for (int j = 0; j < 2; ++j)
        bfr[j] = *(const short8*)&Bs[(wn + j * 16 + l15) * 64 + kc * 32 + quad * 8];
      for (int i = 0; i < 4; ++i)
        for (int j = 0; j < 2; ++j)
          acc[i][j] = MFMA(af[i], bfr[j], acc[i][j]);
    }
    __syncthreads();
  }

  if (Cf) {
    // fp32 + bias: 16 lanes x 4B = full 64B line per quad
    for (int i = 0; i < 4; ++i)
      for (int j = 0; j < 2; ++j) {
        long row = m0 + wm + i * 16 + quad * 4;
        long col = n0 + wn + j * 16 + l15;
        float b = bias ? bias[col] : 0.f;
        for (int r = 0; r < 4; ++r) Cf[(row + r) * (long)ldc + col] = acc[i][j][r] + b;
      }
    return;
  }
  // bf16: acc -> LDS [128][72] -> 16B lane-contiguous stores
  for (int i = 0; i < 4; ++i)
    for (int j = 0; j < 2; ++j)
      for (int r = 0; r < 4; ++r)
        smem[(wm + i * 16 + quad * 4 + r) * 72 + wn + j * 16 + l15] = f2bf(acc[i][j][r]);
  __syncthreads();
  for (int p = 0; p < 4; ++p) {        // 128 rows x 8 chunks(16B) = 1024
    int cid = p * 256 + tid;
    int row = cid >> 3, c = cid & 7;
    short8 v = *(const short8*)&smem[row * 72 + c * 8];
    *(short8*)&Cb[(m0 + row) * (long)ldc + n0 + c * 8] = v;
  }
}

// ---------------- flash attention (unchanged from R6) ----------------
__global__ __launch_bounds__(256, 4)
void attn_kernel(const u16* __restrict__ qp, const u16* __restrict__ kp,
                 const u16* __restrict__ vT, u16* __restrict__ ctx) {
  __shared__ u16 Ks[64 * 128];   // row k: 16B-granule g stored at g^(k&15)
  __shared__ u16 Vs[128 * 64];   // row d: granule g stored at g^(d&7)
  __shared__ u16 Pb[4][16 * 64]; // per-wave P, granule g at g^(row&7)
  const int tid  = threadIdx.x;
  const int wave = tid >> 6, lane = tid & 63;
  const int l15  = lane & 15, quad = lane >> 4;
  const int lin  = blockIdx.x;
  const int xcd  = lin & 7, slot = lin >> 3;           // slot 0..127
  const int pairIdx = xcd * 4 + (slot & 3);            // 0..31 (b,h)
  const int b = pairIdx >> 3, h = pairIdx & 7;
  const int qtile = slot >> 2;                         // 0..31
  const long rowbase = (long)b * 2048 + qtile * 64 + wave * 16;
  const float sc = 0.08838834764831845f * 1.4426950408889634f;  // scale*log2(e)

  short8 aQ[4];
  for (int dc = 0; dc < 4; ++dc)
    aQ[dc] = *(const short8*)&qp[(rowbase + l15) * 1024 + h * 128 + dc * 32 + quad * 8];

  floatx4 O[8] = {};
  float lsum[4] = {};
  const u16* kpb   = kp + ((long)b * 512) * 1024 + h * 128;
  const u16* vbase = vT + ((long)(b * 8 + h) * 128) * 512;

  const int krow = lane >> 4;
  const int kpos = lane & 15;
  const int vrow = lane >> 3;
  const int vpos = lane & 7;

  for (int t = 0; t < 8; ++t) {
    for (int i = 0; i < 4; ++i) {
      int inst = wave * 4 + i;
      int row  = inst * 4 + krow;
      int g    = kpos ^ (row & 15);
      async_lds16(kpb + (long)(t * 64 + row) * 1024 + g * 8, &Ks[inst * 512]);
    }
    for (int i = 0; i < 4; ++i) {
      int inst = wave * 4 + i;
      int d    = inst * 8 + vrow;
      int g    = vpos ^ (d & 7);
      async_lds16(vbase + (long)d * 512 + t * 64 + g * 8, &Vs[inst * 512]);
    }
    __syncthreads();

    floatx4 S[4] = {};
    for (int dc = 0; dc < 4; ++dc)
      for (int ks = 0; ks < 4; ++ks) {
        int k = ks * 16 + l15;
        short8 bk = *(const short8*)&Ks[k * 128 + (((dc * 4 + quad) ^ l15) * 8)];
        S[ks] = MFMA(aQ[dc], bk, S[ks]);
      }
    for (int ks = 0; ks < 4; ++ks)
      for (int r = 0; r < 4; ++r) {
        float p = fast_exp2(S[ks][r] * sc);
        lsum[r] += p;
        int row = quad * 4 + r;
        int g   = (ks * 2 + (l15 >> 3)) ^ (row & 7);
        Pb[wave][row * 64 + g * 8 + (l15 & 7)] = f2bf(p);
      }
    short8 aP[2];
    for (int kc = 0; kc < 2; ++kc)
      aP[kc] = *(const short8*)&Pb[wave][l15 * 64 + (((kc * 4 + quad) ^ (l15 & 7)) * 8)];
    for (int j = 0; j < 8; ++j) {
      int d = j * 16 + l15;
      short8 bV0 = *(const short8*)&Vs[d * 64 + ((quad ^ (l15 & 7)) * 8)];
      short8 bV1 = *(const short8*)&Vs[d * 64 + (((4 + quad) ^ (l15 & 7)) * 8)];
      O[j] = MFMA(aP[0], bV0, O[j]);
      O[j] = MFMA(aP[1], bV1, O[j]);
    }
    __syncthreads();
  }

  for (int r = 0; r < 4; ++r) {
    float sum = lsum[r];
    for (int off = 1; off < 16; off <<= 1) sum += __shfl_xor(sum, off);
    lsum[r] = 1.f / sum;
  }
  for (int j = 0; j < 8; ++j)
    for (int r = 0; r < 4; ++r)
      ctx[(rowbase + quad * 4 + r) * 1024 + h * 128 + j * 16 + l15] =
          f2bf(O[j][r] * lsum[r]);
}

extern "C" void kernel_launch(void* const* d_in, const int* in_sizes, int n_in,
                              void* d_out, int out_size, void* d_ws, size_t ws_size,
                              hipStream_t stream) {
  const float* q  = (const float*)d_in[0];
  const float* kv = (const float*)d_in[1];
  const float* Wq = (const float*)d_in[2];
  const float* Wk = (const float*)d_in[3];
  const float* Wv = (const float*)d_in[4];
  const float* Wo = (const float*)d_in[5];
  const float* bo = (const float*)d_in[6];
  float* out = (float*)d_out;

  char* ws = (char*)d_ws;
  u16* q_bf  = (u16*)(ws + 0);              // 16 MB
  u16* kv_bf = (u16*)(ws + 16777216);       //  3 MB
  u16* WqT   = (u16*)(ws + 19922944);       //  2 MB   [1024][1024]
  u16* WkvT  = (u16*)(ws + 22020096);       //  3 MB   [2048][768]
  u16* WoT   = (u16*)(ws + 25165824);       //  2 MB   [1024][1024]
  u16* qp    = (u16*)(ws + 27262976);       // 16 MB   [8192][1024]
  u16* kp    = (u16*)(ws + 44040192);       //  4 MB   [2048][1024]
  u16* vT    = (u16*)(ws + 52428800);       //  4 MB   [B][H][128][512]
  u16* ctx   = (u16*)(ws + 56623104);       // 16 MB   [8192][1024]

  cvt_all<<<4864, 256, 0, stream>>>(q, kv, q_bf, kv_bf);
  transpose_all<<<dim3(16, 16, 4), 256, 0, stream>>>(Wq, Wk, Wv, Wo, WqT, WkvT, WoT);

  // Q projection: M=8192, N=1024 -> 1024 blocks (128x64 tiles)
  gemm_n64<<<1024, 256, 0, stream>>>(q_bf, WqT, qp, nullptr, nullptr, 1024, 1024);
  // fused K+V projection: M=2048, N=2048 -> 256 blocks (128x128 tiles)
  gemm_bt<<<256, 256, 0, stream>>>(kv_bf, WkvT, kp, nullptr, nullptr, vT,
                                   2048, 2048, 768, 1024, 2);

  attn_kernel<<<1024, 256, 0, stream>>>(qp, kp, vT, ctx);

  // output projection + bias: fp32 out -> 1024 blocks (128x64 tiles)
  gemm_n64<<<1024, 256, 0, stream>>>(ctx, WoT, nullptr, out, bo, 1024, 1024);
}

// Round 11
// 211.166 us; speedup vs baseline: 1.0090x; 1.0090x over previous
//
#include <hip/hip_runtime.h>
#include <hip/hip_cooperative_groups.h>

namespace cg = cooperative_groups;

// CrossAttention on MI355X (gfx950), bf16 MFMA path.
// B=4, Lq=2048, Lkv=512, dim_q=1024, dim_kv=768, H=8, hd=128.
// R11: cooperative mega-kernel fusing {Q-proj + KV-proj} -> attn -> O-proj
//      with grid.sync() between phases. Evidence: R6->R7 showed ~10us per
//      dispatch gap; 6->3 dispatches saves ~30us. Grid 1024 = 4 blocks/CU
//      (LDS 40960B, VGPR<=128 via __launch_bounds__(256,4)). Phase bodies are
//      the R7/R6-proven gemm/attn logic, single call sites. Host checks
//      occupancy and falls back to the 6-launch R7 path if coop can't fit.

typedef unsigned short u16;
typedef unsigned int u32;
using short8  = __attribute__((ext_vector_type(8))) short;   // 8 x bf16 (4 VGPRs)
using floatx4 = __attribute__((ext_vector_type(4))) float;

__device__ inline u16 f2bf(float x) {
  union { float f; u32 u; } v; v.f = x;
  u32 r = (v.u + 0x7fffu + ((v.u >> 16) & 1u)) >> 16;  // RNE
  return (u16)r;
}

__device__ inline float fast_exp2(float x) {
#if __has_builtin(__builtin_amdgcn_exp2f)
  return __builtin_amdgcn_exp2f(x);   // v_exp_f32 (natively exp2)
#else
  return exp2f(x);
#endif
}

#define MFMA(a, b, c) __builtin_amdgcn_mfma_f32_16x16x32_bf16(a, b, c, 0, 0, 0)

__device__ inline void async_lds16(const void* g, void* l) {
  __builtin_amdgcn_global_load_lds(
      (const __attribute__((address_space(1))) void*)g,
      (__attribute__((address_space(3))) void*)l, 16, 0, 0);
}

// ------------- fp32 -> bf16 cast, q and kv in one launch -------------
__global__ void cvt_all(const float* __restrict__ q, const float* __restrict__ kv,
                        u16* __restrict__ q_bf, u16* __restrict__ kv_bf) {
  int i = blockIdx.x * 256 + threadIdx.x;
  const float* src; u16* dst; int idx;
  if (i < 1048576) { src = q;  dst = q_bf;  idx = i; }
  else             { src = kv; dst = kv_bf; idx = i - 1048576; }
  float4 a = ((const float4*)src)[2 * idx];
  float4 b = ((const float4*)src)[2 * idx + 1];
  u16 t[8] = {f2bf(a.x), f2bf(a.y), f2bf(a.z), f2bf(a.w),
              f2bf(b.x), f2bf(b.y), f2bf(b.z), f2bf(b.w)};
  ((short8*)dst)[idx] = *(short8*)t;
}

// ------------- all four W [K][N] fp32 -> Wt [N][K] bf16, one launch -------------
__global__ __launch_bounds__(256)
void transpose_all(const float* __restrict__ Wq, const float* __restrict__ Wk,
                   const float* __restrict__ Wv, const float* __restrict__ Wo,
                   u16* __restrict__ WqT, u16* __restrict__ WkvT, u16* __restrict__ WoT) {
  __shared__ float tile[64][68];
  const int z = blockIdx.z;
  const float* W; u16* Wt; int K;
  if      (z == 0) { W = Wq; Wt = WqT;               K = 1024; }
  else if (z == 1) { W = Wk; Wt = WkvT;              K = 768;  }
  else if (z == 2) { W = Wv; Wt = WkvT + 1024 * 768; K = 768;  }
  else             { W = Wo; Wt = WoT;               K = 1024; }
  const int k0 = blockIdx.y * 64, n0 = blockIdx.x * 64;
  if (k0 >= K) return;
  const int N = 1024;
  const int t = threadIdx.x;
  for (int p = 0; p < 4; ++p) {
    int cid = p * 256 + t;
    int row = cid >> 4, c = cid & 15;
    float4 v = *(const float4*)&W[(long)(k0 + row) * N + n0 + c * 4];
    tile[row][c * 4 + 0] = v.x; tile[row][c * 4 + 1] = v.y;
    tile[row][c * 4 + 2] = v.z; tile[row][c * 4 + 3] = v.w;
  }
  __syncthreads();
  for (int p = 0; p < 2; ++p) {
    int oc = p * 256 + t;
    int n = oc >> 3, c = oc & 7;
    u16 tmp[8];
    for (int s = 0; s < 8; ++s) tmp[s] = f2bf(tile[c * 8 + s][n]);
    *(short8*)&Wt[(long)(n0 + n) * K + k0 + c * 8] = *(short8*)tmp;
  }
}

// ---------------- bf16 GEMM body (R7-proven logic) ----------------
__device__ __forceinline__
void gemm_body(const u16* __restrict__ A, const u16* __restrict__ Bt,
               u16* __restrict__ Cb, float* __restrict__ Cf,
               const float* __restrict__ bias, u16* __restrict__ vt_out,
               int K, int ldc, int lin, int mt_per_xcd, u16* smem) {
  u16* As = smem;                           // [128][64]
  u16* Bs = smem + 8192;                    // [128][64]
  const int tid  = threadIdx.x;
  const int wave = tid >> 6, lane = tid & 63;
  const int l15  = lane & 15, quad = lane >> 4;
  const int wm   = (wave >> 1) * 64, wn = (wave & 1) * 64;
  const int xcd  = lin & 7, slot = lin >> 3;
  const int mt   = xcd * mt_per_xcd + (slot % mt_per_xcd);
  const int nti  = slot / mt_per_xcd;
  const long m0  = (long)mt * 128, n0 = (long)nti * 128;
  const int lrow = lane >> 3;
  const int lk   = (lane & 7) * 8;

  floatx4 acc[4][4] = {};

  for (int k0 = 0; k0 < K; k0 += 64) {
    for (int c = 0; c < 4; ++c) {
      int rbase = (wave * 4 + c) * 8;
      async_lds16(A  + (m0 + rbase + lrow) * (long)K + k0 + lk, &As[(wave * 4 + c) * 512]);
      async_lds16(Bt + (n0 + rbase + lrow) * (long)K + k0 + lk, &Bs[(wave * 4 + c) * 512]);
    }
    __syncthreads();
    for (int kc = 0; kc < 2; ++kc) {
      short8 af[4], bfr[4];
      for (int i = 0; i < 4; ++i)
        af[i] = *(const short8*)&As[(wm + i * 16 + l15) * 64 + kc * 32 + quad * 8];
      for (int j = 0; j < 4; ++j)
        bfr[j] = *(const short8*)&Bs[(wn + j * 16 + l15) * 64 + kc * 32 + quad * 8];
      for (int i = 0; i < 4; ++i)
        for (int j = 0; j < 4; ++j)
          acc[i][j] = MFMA(af[i], bfr[j], acc[i][j]);
    }
    __syncthreads();
  }

  if (Cf) {
    for (int i = 0; i < 4; ++i)
      for (int j = 0; j < 4; ++j) {
        long row = m0 + wm + i * 16 + quad * 4;
        long col = n0 + wn + j * 16 + l15;
        float b = bias ? bias[col] : 0.f;
        for (int r = 0; r < 4; ++r) Cf[(row + r) * (long)ldc + col] = acc[i][j][r] + b;
      }
    return;
  }
  for (int i = 0; i < 4; ++i)
    for (int j = 0; j < 4; ++j)
      for (int r = 0; r < 4; ++r)
        smem[(wm + i * 16 + quad * 4 + r) * 138 + wn + j * 16 + l15] = f2bf(acc[i][j][r]);
  __syncthreads();
  if (vt_out && nti >= 8) {
    const int h  = nti - 8;
    const int bq = (int)(m0 >> 9);
    const int l0 = (int)(m0 & 511);
    u16* vbase = vt_out + ((long)(bq * 8 + h) * 128) * 512;
    for (int p = 0; p < 8; ++p) {
      int cid = p * 256 + tid;
      int d = cid >> 4, c = cid & 15;
      u16 tmp[8];
      for (int s = 0; s < 8; ++s) tmp[s] = smem[(c * 8 + s) * 138 + d];
      *(short8*)&vbase[(long)d * 512 + l0 + c * 8] = *(short8*)tmp;
    }
  } else {
    for (int p = 0; p < 8; ++p) {
      int cid = p * 256 + tid;
      int row = cid >> 4, c = cid & 15;
      short8 v = *(const short8*)&smem[row * 138 + c * 8];
      *(short8*)&Cb[(m0 + row) * (long)ldc + n0 + c * 8] = v;
    }
  }
}

// ---------------- flash attention body (R6-proven logic) ----------------
__device__ __forceinline__
void attn_body(const u16* __restrict__ qp, const u16* __restrict__ kp,
               const u16* __restrict__ vT, u16* __restrict__ ctx,
               int lin, u16* smem) {
  u16* Ks = smem;            // [64 k][128 d], granule g at g^(k&15)
  u16* Vs = smem + 8192;     // [128 d][64 k], granule g at g^(d&7)
  const int tid  = threadIdx.x;
  const int wave = tid >> 6, lane = tid & 63;
  u16* Pw = smem + 16384 + wave * 1024;  // per-wave P [16 r][64 k], g^(row&7)
  const int l15  = lane & 15, quad = lane >> 4;
  const int xcd  = lin & 7, slot = lin >> 3;           // slot 0..127
  const int pairIdx = xcd * 4 + (slot & 3);            // 0..31 (b,h)
  const int b = pairIdx >> 3, h = pairIdx & 7;
  const int qtile = slot >> 2;                         // 0..31
  const long rowbase = (long)b * 2048 + qtile * 64 + wave * 16;
  const float sc = 0.08838834764831845f * 1.4426950408889634f;  // scale*log2(e)

  short8 aQ[4];
  for (int dc = 0; dc < 4; ++dc)
    aQ[dc] = *(const short8*)&qp[(rowbase + l15) * 1024 + h * 128 + dc * 32 + quad * 8];

  floatx4 O[8] = {};
  float lsum[4] = {};
  const u16* kpb   = kp + ((long)b * 512) * 1024 + h * 128;
  const u16* vbase = vT + ((long)(b * 8 + h) * 128) * 512;

  const int krow = lane >> 4;
  const int kpos = lane & 15;
  const int vrow = lane >> 3;
  const int vpos = lane & 7;

  for (int t = 0; t < 8; ++t) {
    for (int i = 0; i < 4; ++i) {
      int inst = wave * 4 + i;
      int row  = inst * 4 + krow;
      int g    = kpos ^ (row & 15);
      async_lds16(kpb + (long)(t * 64 + row) * 1024 + g * 8, &Ks[inst * 512]);
    }
    for (int i = 0; i < 4; ++i) {
      int inst = wave * 4 + i;
      int d    = inst * 8 + vrow;
      int g    = vpos ^ (d & 7);
      async_lds16(vbase + (long)d * 512 + t * 64 + g * 8, &Vs[inst * 512]);
    }
    __syncthreads();

    floatx4 S[4] = {};
    for (int dc = 0; dc < 4; ++dc)
      for (int ks = 0; ks < 4; ++ks) {
        int k = ks * 16 + l15;
        short8 bk = *(const short8*)&Ks[k * 128 + (((dc * 4 + quad) ^ l15) * 8)];
        S[ks] = MFMA(aQ[dc], bk, S[ks]);
      }
    for (int ks = 0; ks < 4; ++ks)
      for (int r = 0; r < 4; ++r) {
        float p = fast_exp2(S[ks][r] * sc);
        lsum[r] += p;
        int row = quad * 4 + r;
        int g   = (ks * 2 + (l15 >> 3)) ^ (row & 7);
        Pw[row * 64 + g * 8 + (l15 & 7)] = f2bf(p);
      }
    short8 aP[2];
    for (int kc = 0; kc < 2; ++kc)
      aP[kc] = *(const short8*)&Pw[l15 * 64 + (((kc * 4 + quad) ^ (l15 & 7)) * 8)];
    for (int j = 0; j < 8; ++j) {
      int d = j * 16 + l15;
      short8 bV0 = *(const short8*)&Vs[d * 64 + ((quad ^ (l15 & 7)) * 8)];
      short8 bV1 = *(const short8*)&Vs[d * 64 + (((4 + quad) ^ (l15 & 7)) * 8)];
      O[j] = MFMA(aP[0], bV0, O[j]);
      O[j] = MFMA(aP[1], bV1, O[j]);
    }
    __syncthreads();
  }

  for (int r = 0; r < 4; ++r) {
    float sum = lsum[r];
    for (int off = 1; off < 16; off <<= 1) sum += __shfl_xor(sum, off);
    lsum[r] = 1.f / sum;
  }
  for (int j = 0; j < 8; ++j)
    for (int r = 0; r < 4; ++r)
      ctx[(rowbase + quad * 4 + r) * 1024 + h * 128 + j * 16 + l15] =
          f2bf(O[j][r] * lsum[r]);
}

// ---------------- cooperative mega-kernel: proj -> attn -> oproj ----------------
// grid 1024 x 256, LDS 40960 B, 4 blocks/CU (all co-resident).
__global__ __launch_bounds__(256, 4)
void mega(const u16* q_bf, const u16* WqT, const u16* kv_bf, const u16* WkvT,
          const u16* WoT, u16* qp, u16* kp, u16* vT, u16* ctx,
          float* out, const float* bo) {
  __shared__ u16 smem[20480];   // 40960 B: gemm uses 17664, attn uses 20480
  cg::grid_group g = cg::this_grid();
  const int bid = blockIdx.x;

  // P2: Q-projection (bid 0..511) + fused KV-projection (bid 512..767)
  if (bid < 768) {
    const bool isQ = bid < 512;
    gemm_body(isQ ? q_bf : kv_bf, isQ ? WqT : WkvT, isQ ? qp : kp,
              nullptr, nullptr, isQ ? (u16*)nullptr : vT,
              isQ ? 1024 : 768, 1024, isQ ? bid : bid - 512, isQ ? 8 : 2, smem);
  }
  g.sync();
  // P3: attention, all 1024 blocks
  attn_body(qp, kp, vT, ctx, bid, smem);
  g.sync();
  // P4: O-projection (bid 0..511), fp32 out + bias
  if (bid < 512)
    gemm_body(ctx, WoT, nullptr, out, bo, nullptr, 1024, 1024, bid, 8, smem);
}

// ---------------- fallback standalone kernels (R7 path) ----------------
__global__ __launch_bounds__(256)
void k_proj_q(const u16* __restrict__ q_bf, const u16* __restrict__ WqT,
              u16* __restrict__ qp) {
  __shared__ u16 smem[17664];
  gemm_body(q_bf, WqT, qp, nullptr, nullptr, nullptr, 1024, 1024, blockIdx.x, 8, smem);
}
__global__ __launch_bounds__(256)
void k_proj_kv(const u16* __restrict__ kv_bf, const u16* __restrict__ WkvT,
               u16* __restrict__ kp, u16* __restrict__ vT) {
  __shared__ u16 smem[17664];
  gemm_body(kv_bf, WkvT, kp, nullptr, nullptr, vT, 768, 1024, blockIdx.x, 2, smem);
}
__global__ __launch_bounds__(256, 4)
void k_attn(const u16* __restrict__ qp, const u16* __restrict__ kp,
            const u16* __restrict__ vT, u16* __restrict__ ctx) {
  __shared__ u16 smem[20480];
  attn_body(qp, kp, vT, ctx, blockIdx.x, smem);
}
__global__ __launch_bounds__(256)
void k_oproj(const u16* __restrict__ ctx, const u16* __restrict__ WoT,
             float* __restrict__ out, const float* __restrict__ bo) {
  __shared__ u16 smem[17664];
  gemm_body(ctx, WoT, nullptr, out, bo, nullptr, 1024, 1024, blockIdx.x, 8, smem);
}

extern "C" void kernel_launch(void* const* d_in, const int* in_sizes, int n_in,
                              void* d_out, int out_size, void* d_ws, size_t ws_size,
                              hipStream_t stream) {
  const float* q  = (const float*)d_in[0];
  const float* kv = (const float*)d_in[1];
  const float* Wq = (const float*)d_in[2];
  const float* Wk = (const float*)d_in[3];
  const float* Wv = (const float*)d_in[4];
  const float* Wo = (const float*)d_in[5];
  const float* bo = (const float*)d_in[6];
  float* out = (float*)d_out;

  char* ws = (char*)d_ws;
  u16* q_bf  = (u16*)(ws + 0);              // 16 MB
  u16* kv_bf = (u16*)(ws + 16777216);       //  3 MB
  u16* WqT   = (u16*)(ws + 19922944);       //  2 MB   [1024][1024]
  u16* WkvT  = (u16*)(ws + 22020096);       //  3 MB   [2048][768]
  u16* WoT   = (u16*)(ws + 25165824);       //  2 MB   [1024][1024]
  u16* qp    = (u16*)(ws + 27262976);       // 16 MB   [8192][1024]
  u16* kp    = (u16*)(ws + 44040192);       //  4 MB   [2048][1024]
  u16* vT    = (u16*)(ws + 52428800);       //  4 MB   [B][H][128][512]
  u16* ctx   = (u16*)(ws + 56623104);       // 16 MB   [8192][1024]

  cvt_all<<<4864, 256, 0, stream>>>(q, kv, q_bf, kv_bf);
  transpose_all<<<dim3(16, 16, 4), 256, 0, stream>>>(Wq, Wk, Wv, Wo, WqT, WkvT, WoT);

  // deterministic per-device decision (same every call; pure host query)
  int maxb = 0;
  hipError_t oe = hipOccupancyMaxActiveBlocksPerMultiprocessor(
      &maxb, (const void*)mega, 256, 0);
  if (oe == hipSuccess && maxb >= 4) {
    void* args[] = {(void*)&q_bf, (void*)&WqT, (void*)&kv_bf, (void*)&WkvT,
                    (void*)&WoT, (void*)&qp, (void*)&kp, (void*)&vT,
                    (void*)&ctx, (void*)&out, (void*)&bo};
    hipLaunchCooperativeKernel((const void*)mega, dim3(1024), dim3(256),
                               args, 0, stream);
  } else {
    k_proj_q<<<512, 256, 0, stream>>>(q_bf, WqT, qp);
    k_proj_kv<<<256, 256, 0, stream>>>(kv_bf, WkvT, kp, vT);
    k_attn<<<1024, 256, 0, stream>>>(qp, kp, vT, ctx);
    k_oproj<<<512, 256, 0, stream>>>(ctx, WoT, out, bo);
  }
}